// Round 5
// baseline (467.012 us; speedup 1.0000x reference)
//
#include <hip/hip_runtime.h>

static constexpr float kEps = 1e-5f;

using bf16x8 = __attribute__((ext_vector_type(8))) short;
using f32x4 = __attribute__((ext_vector_type(4))) float;
using f32x2 = __attribute__((ext_vector_type(2))) float;

constexpr int ilog2(int n) { return n <= 1 ? 0 : 1 + ilog2(n / 2); }

// round-to-nearest-even f32 -> bf16 bits
__device__ inline unsigned bf_rne(float v) {
  unsigned u = __float_as_uint(v);
  return (u + 0x7FFFu + ((u >> 16) & 1u)) >> 16;
}
// split f32 into bf16 hi + bf16 lo (v ~= hi + lo)
__device__ inline void split_bf(float v, unsigned short& h, unsigned short& l) {
  unsigned hb = bf_rne(v);
  h = (unsigned short)hb;
  float hf = __uint_as_float(hb << 16);
  l = (unsigned short)bf_rne(v - hf);
}

// packed dual-FP32 FMA: d = a*b + d (per 32-bit half)
__device__ inline void pk_fma(f32x2& d, f32x2 a, f32x2 b) {
  asm volatile("v_pk_fma_f32 %0, %1, %2, %0" : "+v"(d) : "v"(a), "v"(b));
}

// ---------------------------------------------------------------------------
// Repack bodies (device functions, fused into one kernel)
// ---------------------------------------------------------------------------
__device__ inline void repack_s1_body(int idx, const float* __restrict__ w,
                                      const float* __restrict__ g,
                                      const float* __restrict__ b,
                                      const float* __restrict__ m,
                                      const float* __restrict__ v,
                                      float* __restrict__ wT,
                                      float* __restrict__ bias) {
  constexpr int CIN = 4, COUT = 32, total = COUT * CIN * 27;
  if (idx < COUT) {
    float inv = g[idx] * rsqrtf(v[idx] + kEps);
    bias[idx] = b[idx] - m[idx] * inv;
  }
  if (idx < total) {
    int cout = idx % COUT;
    int ck = idx / COUT;
    int cin = ck / 27;
    int k = ck % 27;
    float inv = g[cout] * rsqrtf(v[cout] + kEps);
    wT[idx] = w[(cout * CIN + cin) * 27 + k] * inv;
  }
}

template <int CIN, int COUT>
__device__ inline void repack_bf_body(int idx, const float* __restrict__ w,
                                      const float* __restrict__ g,
                                      const float* __restrict__ b,
                                      const float* __restrict__ m,
                                      const float* __restrict__ v,
                                      unsigned short* __restrict__ wh,
                                      unsigned short* __restrict__ wl,
                                      float* __restrict__ bias) {
  constexpr int total = 27 * COUT * CIN;
  constexpr int LC = ilog2(CIN), LO = ilog2(COUT);
  if (idx < COUT) {
    float inv = g[idx] * rsqrtf(v[idx] + kEps);
    bias[idx] = b[idx] - m[idx] * inv;
  }
  if (idx < total) {
    int ci = idx & (CIN - 1);
    int t = idx >> LC;
    int co = t & (COUT - 1);
    int tap = t >> LO;
    float inv = g[co] * rsqrtf(v[co] + kEps);
    float val = w[((size_t)co * CIN + ci) * 27 + tap] * inv;
    unsigned short h, l;
    split_bf(val, h, l);
    wh[idx] = h;
    wl[idx] = l;
  }
}

// All weight repacks in ONE launch. Block ranges:
// [0,14) s1 | [14,230) s2 | [230,1094) s3 | [1094,4550) s4 |
// [4550,18374) s5 | [18374,18886) wout
__global__ __launch_bounds__(256) void repack_all(
    const float* w1, const float* g1, const float* b1, const float* m1, const float* v1,
    const float* w2, const float* g2, const float* b2, const float* m2, const float* v2,
    const float* w3, const float* g3, const float* b3, const float* m3, const float* v3,
    const float* w4, const float* g4, const float* b4, const float* m4, const float* v4,
    const float* w5, const float* g5, const float* b5, const float* m5, const float* v5,
    const float* w_out, float* wt1, unsigned short* w2h, unsigned short* w2l,
    unsigned short* w3h, unsigned short* w3l, unsigned short* w4h, unsigned short* w4l,
    unsigned short* w5h, unsigned short* w5l, float* woutT, float* bs1, float* bs2,
    float* bs3, float* bs4, float* bs5) {
  int blk = blockIdx.x;
  int tid = threadIdx.x;
  if (blk < 14) {
    repack_s1_body(blk * 256 + tid, w1, g1, b1, m1, v1, wt1, bs1);
  } else if (blk < 230) {
    repack_bf_body<32, 64>((blk - 14) * 256 + tid, w2, g2, b2, m2, v2, w2h, w2l, bs2);
  } else if (blk < 1094) {
    repack_bf_body<64, 128>((blk - 230) * 256 + tid, w3, g3, b3, m3, v3, w3h, w3l, bs3);
  } else if (blk < 4550) {
    repack_bf_body<128, 256>((blk - 1094) * 256 + tid, w4, g4, b4, m4, v4, w4h, w4l, bs4);
  } else if (blk < 18374) {
    repack_bf_body<256, 512>((blk - 4550) * 256 + tid, w5, g5, b5, m5, v5, w5h, w5l, bs5);
  } else {
    int idx = (blk - 18374) * 256 + tid;  // = c*256 + co
    int co = idx & 255;
    int c = idx >> 8;
    woutT[idx] = w_out[(size_t)co * 512 + c];
  }
}

// ---------------------------------------------------------------------------
// Stage 1: fp32 direct conv (cin=4) with v_pk_fma_f32 (16 float2 accs)
// -> parity-split channels-last bf16 hi/lo [b][pz][py][px][32^3][32]
// ---------------------------------------------------------------------------
__global__ __launch_bounds__(256) void conv1_direct(
    const float* __restrict__ in, const float* __restrict__ wT,
    const float* __restrict__ bias, unsigned short* __restrict__ outh,
    unsigned short* __restrict__ outl) {
  constexpr int DI = 128, CIN = 4, COUT = 32;
  int tid = blockIdx.x * 256 + threadIdx.x;
  int x = tid & 63;
  int t = tid >> 6;
  int y = t & 63;
  t >>= 6;
  int z = t & 63;
  int bb = t >> 6;

  f32x2 acc[16];
#pragma unroll
  for (int i = 0; i < 16; ++i) acc[i] = (f32x2){0.f, 0.f};

  const float* inb = in + (size_t)bb * CIN * DI * DI * DI;
  for (int cin = 0; cin < CIN; ++cin) {
    const float* inc = inb + (size_t)cin * DI * DI * DI;
#pragma unroll
    for (int kz = 0; kz < 3; ++kz) {
      int iz = 2 * z + kz - 1;
      if (iz < 0) continue;
#pragma unroll
      for (int ky = 0; ky < 3; ++ky) {
        int iy = 2 * y + ky - 1;
        if (iy < 0) continue;
        const float* row = inc + ((size_t)iz * DI + iy) * DI;
        // 3 taps need row[2x-1], row[2x], row[2x+1]: 1 f32x2 + 1 guarded scalar
        f32x2 rv = *reinterpret_cast<const f32x2*>(row + 2 * x);
        float xm = (x > 0) ? row[2 * x - 1] : 0.f;
        const float* wbase = wT + ((size_t)cin * 27 + (kz * 3 + ky) * 3) * COUT;
        {
          f32x2 xv2 = (f32x2){xm, xm};
#pragma unroll
          for (int i = 0; i < 16; ++i)
            pk_fma(acc[i], *reinterpret_cast<const f32x2*>(wbase + 2 * i), xv2);
        }
        {
          f32x2 xv2 = (f32x2){rv.x, rv.x};
#pragma unroll
          for (int i = 0; i < 16; ++i)
            pk_fma(acc[i], *reinterpret_cast<const f32x2*>(wbase + COUT + 2 * i), xv2);
        }
        {
          f32x2 xv2 = (f32x2){rv.y, rv.y};
#pragma unroll
          for (int i = 0; i < 16; ++i)
            pk_fma(acc[i], *reinterpret_cast<const f32x2*>(wbase + 2 * COUT + 2 * i), xv2);
        }
      }
    }
  }
  int pidx = (z & 1) * 4 + (y & 1) * 2 + (x & 1);
  size_t sub = (((size_t)(z >> 1) * 32) + (y >> 1)) * 32 + (x >> 1);
  size_t op = (((size_t)bb * 8 + pidx) * 32768 + sub) * COUT;
#pragma unroll
  for (int i = 0; i < COUT; ++i) {
    float r = fmaxf(acc[i >> 1][i & 1] + bias[i], 0.f);
    unsigned short h, l;
    split_bf(r, h, l);
    outh[op + i] = h;
    outl[op + i] = l;
  }
}

// ---------------------------------------------------------------------------
// MFMA implicit-GEMM conv (3x3x3 stride-2 pad-1) on parity-split input.
// Input: [b][pz][py][px][DO^3][CIN]. Tap (kz,ky,kx): p=(k!=1), d=(k==0).
// 3-product split: acc += Ah*Bh + Ah*Bl + Al*Bh (fp32 accumulate).
// Block = 4 waves; wave tile = (MREP*16) M x 64 N.
// ---------------------------------------------------------------------------
template <int CIN, int COUT, int DO, int SK, int MREP>
__global__ __launch_bounds__(256) void conv_mfma(
    const unsigned short* __restrict__ inh, const unsigned short* __restrict__ inl,
    const unsigned short* __restrict__ wh, const unsigned short* __restrict__ wl,
    const float* __restrict__ bias, unsigned short* __restrict__ outh,
    unsigned short* __restrict__ outl, float* __restrict__ partial) {
  constexpr int M = 2 * DO * DO * DO;
  constexpr int TAPS = 27 / SK;
  constexpr int KCPT = CIN / 32;
  constexpr int LD = ilog2(DO);
  constexpr int SUB = DO * DO * DO;

  const int lane = threadIdx.x & 63;
  const int wv = threadIdx.x >> 6;
  const int mWave = (blockIdx.x * 4 + wv) * (MREP * 16);
  const int nBase = blockIdx.y * 64;
  const int skid = blockIdx.z;
  const int mlane = lane & 15;
  const int kgrp = lane >> 4;

  int xf[MREP], yf[MREP], zf[MREP], bf_[MREP];
#pragma unroll
  for (int f = 0; f < MREP; ++f) {
    int m = mWave + f * 16 + mlane;
    xf[f] = m & (DO - 1);
    yf[f] = (m >> LD) & (DO - 1);
    zf[f] = (m >> (2 * LD)) & (DO - 1);
    bf_[f] = m >> (3 * LD);
  }

  f32x4 acc[MREP][4];
#pragma unroll
  for (int f = 0; f < MREP; ++f)
#pragma unroll
    for (int q = 0; q < 4; ++q) acc[f][q] = (f32x4){0.f, 0.f, 0.f, 0.f};

  for (int tp = 0; tp < TAPS; ++tp) {
    const int tap = skid * TAPS + tp;
    const int kz = tap / 9;
    const int kr = tap - kz * 9;
    const int ky = kr / 3;
    const int kx = kr - ky * 3;
    const int pidx = (kz != 1) * 4 + (ky != 1) * 2 + (kx != 1);
    const int dz = (kz == 0), dy = (ky == 0), dx = (kx == 0);

    const size_t woff = (size_t)tap * COUT * CIN + (size_t)(nBase + mlane) * CIN + kgrp * 8;
    const unsigned short* wbh = wh + woff;
    const unsigned short* wbl = wl + woff;

    long long aoff[MREP];
    bool valid[MREP];
#pragma unroll
    for (int f = 0; f < MREP; ++f) {
      int sx = xf[f] - dx, sy = yf[f] - dy, sz = zf[f] - dz;
      valid[f] = ((sx | sy | sz) >= 0);
      aoff[f] = ((long long)(bf_[f] * 8 + pidx) * SUB + (sz * DO + sy) * DO + sx) * CIN +
                kgrp * 8;
    }

#pragma unroll
    for (int kc = 0; kc < KCPT; ++kc) {
      bf16x8 Ah[MREP], Al[MREP];
#pragma unroll
      for (int f = 0; f < MREP; ++f) {
        Ah[f] = (bf16x8){0, 0, 0, 0, 0, 0, 0, 0};
        Al[f] = (bf16x8){0, 0, 0, 0, 0, 0, 0, 0};
        if (valid[f]) {
          Ah[f] = *reinterpret_cast<const bf16x8*>(inh + aoff[f] + kc * 32);
          Al[f] = *reinterpret_cast<const bf16x8*>(inl + aoff[f] + kc * 32);
        }
      }
#pragma unroll
      for (int nq = 0; nq < 4; ++nq) {
        bf16x8 Bh = *reinterpret_cast<const bf16x8*>(wbh + (size_t)nq * 16 * CIN + kc * 32);
        bf16x8 Bl = *reinterpret_cast<const bf16x8*>(wbl + (size_t)nq * 16 * CIN + kc * 32);
#pragma unroll
        for (int f = 0; f < MREP; ++f) {
          acc[f][nq] = __builtin_amdgcn_mfma_f32_16x16x32_bf16(Ah[f], Bh, acc[f][nq], 0, 0, 0);
          acc[f][nq] = __builtin_amdgcn_mfma_f32_16x16x32_bf16(Ah[f], Bl, acc[f][nq], 0, 0, 0);
          acc[f][nq] = __builtin_amdgcn_mfma_f32_16x16x32_bf16(Al[f], Bh, acc[f][nq], 0, 0, 0);
        }
      }
    }
  }

  if constexpr (SK == 1) {
    constexpr int HD = DO / 2;
#pragma unroll
    for (int f = 0; f < MREP; ++f) {
#pragma unroll
      for (int nq = 0; nq < 4; ++nq) {
        const int n = nBase + nq * 16 + mlane;
        const float bv = bias[n];
#pragma unroll
        for (int r = 0; r < 4; ++r) {
          const int mrow = mWave + f * 16 + kgrp * 4 + r;
          const int ox = mrow & (DO - 1);
          const int oy = (mrow >> LD) & (DO - 1);
          const int oz = (mrow >> (2 * LD)) & (DO - 1);
          const int ob = mrow >> (3 * LD);
          const int pp = (oz & 1) * 4 + (oy & 1) * 2 + (ox & 1);
          const size_t sub = (((size_t)(oz >> 1) * HD) + (oy >> 1)) * HD + (ox >> 1);
          const size_t addr = (((size_t)ob * 8 + pp) * (HD * HD * HD) + sub) * COUT + n;
          float vv = fmaxf(acc[f][nq][r] + bv, 0.f);
          unsigned short h, l;
          split_bf(vv, h, l);
          outh[addr] = h;
          outl[addr] = l;
        }
      }
    }
  } else {
#pragma unroll
    for (int f = 0; f < MREP; ++f) {
#pragma unroll
      for (int nq = 0; nq < 4; ++nq) {
        const int n = nBase + nq * 16 + mlane;
#pragma unroll
        for (int r = 0; r < 4; ++r) {
          const int mrow = mWave + f * 16 + kgrp * 4 + r;
          partial[((size_t)skid * M + mrow) * COUT + n] = acc[f][nq][r];
        }
      }
    }
  }
}

// ---------------------------------------------------------------------------
// Reduce split-K fp32 partials + bias + ReLU -> parity-split bf16 hi/lo
// ---------------------------------------------------------------------------
template <int COUT, int SK, int M, int DOP>
__global__ __launch_bounds__(256) void reduce_split(
    const float* __restrict__ partial, const float* __restrict__ bias,
    unsigned short* __restrict__ oh, unsigned short* __restrict__ ol) {
  constexpr int LD = ilog2(DOP);
  constexpr int HD = DOP / 2;
  int idx = blockIdx.x * 256 + threadIdx.x;  // mrow*COUT + n
  int n = idx & (COUT - 1);
  int mrow = idx / COUT;
  float s = 0.f;
#pragma unroll
  for (int k = 0; k < SK; ++k) s += partial[(size_t)k * M * COUT + idx];
  float v = fmaxf(s + bias[n], 0.f);
  const int ox = mrow & (DOP - 1);
  const int oy = (mrow >> LD) & (DOP - 1);
  const int oz = (mrow >> (2 * LD)) & (DOP - 1);
  const int ob = mrow >> (3 * LD);
  const int pp = (oz & 1) * 4 + (oy & 1) * 2 + (ox & 1);
  const size_t sub = (((size_t)(oz >> 1) * HD) + (oy >> 1)) * HD + (ox >> 1);
  const size_t addr = (((size_t)ob * 8 + pp) * (HD * HD * HD) + sub) * COUT + n;
  unsigned short h, l;
  split_bf(v, h, l);
  oh[addr] = h;
  ol[addr] = l;
}

// ---------------------------------------------------------------------------
// Fused: stage-5 split-K reduce (27 partials) + bias + ReLU + 1x1x1 conv.
// p5 layout [k][128][512]; wt [512][256]; out NCDHW [2][256][64]
// ---------------------------------------------------------------------------
__global__ __launch_bounds__(256) void final_fused(
    const float* __restrict__ p5, const float* __restrict__ bias,
    const float* __restrict__ wt, float* __restrict__ out) {
  __shared__ float h[512];
  int p = blockIdx.x;  // 0..127 = b*64 + s
  int t = threadIdx.x;
#pragma unroll
  for (int cc = 0; cc < 2; ++cc) {
    int c = t + cc * 256;
    float s = 0.f;
#pragma unroll
    for (int k = 0; k < 27; ++k) s += p5[((size_t)k * 128 + p) * 512 + c];
    h[c] = fmaxf(s + bias[c], 0.f);
  }
  __syncthreads();
  int b = p >> 6, sp = p & 63;
  float acc = 0.f;
#pragma unroll 8
  for (int c = 0; c < 512; ++c) acc = fmaf(h[c], wt[(size_t)c * 256 + t], acc);
  out[((size_t)b * 256 + t) * 64 + sp] = acc;
}

// ---------------------------------------------------------------------------
extern "C" void kernel_launch(void* const* d_in, const int* in_sizes, int n_in,
                              void* d_out, int out_size, void* d_ws,
                              size_t ws_size, hipStream_t stream) {
  const float* x = (const float*)d_in[0];
  const float* w1 = (const float*)d_in[1];
  const float* g1 = (const float*)d_in[2];
  const float* bb1 = (const float*)d_in[3];
  const float* m1 = (const float*)d_in[4];
  const float* v1 = (const float*)d_in[5];
  const float* w2 = (const float*)d_in[6];
  const float* g2 = (const float*)d_in[7];
  const float* bb2 = (const float*)d_in[8];
  const float* m2 = (const float*)d_in[9];
  const float* v2 = (const float*)d_in[10];
  const float* w3 = (const float*)d_in[11];
  const float* g3 = (const float*)d_in[12];
  const float* bb3 = (const float*)d_in[13];
  const float* m3 = (const float*)d_in[14];
  const float* v3 = (const float*)d_in[15];
  const float* w4 = (const float*)d_in[16];
  const float* g4 = (const float*)d_in[17];
  const float* bb4 = (const float*)d_in[18];
  const float* m4 = (const float*)d_in[19];
  const float* v4 = (const float*)d_in[20];
  const float* w5 = (const float*)d_in[21];
  const float* g5 = (const float*)d_in[22];
  const float* bb5 = (const float*)d_in[23];
  const float* m5 = (const float*)d_in[24];
  const float* v5 = (const float*)d_in[25];
  const float* w_out = (const float*)d_in[26];
  (void)in_sizes; (void)n_in; (void)out_size; (void)ws_size;

  char* base = (char*)d_ws;
  size_t off = 0;
  auto take = [&](size_t bytes) {
    char* p = base + off;
    off = (off + bytes + 255) & ~(size_t)255;
    return p;
  };
  float* wt1 = (float*)take(3456 * 4);
  unsigned short* w2h = (unsigned short*)take(55296 * 2);
  unsigned short* w2l = (unsigned short*)take(55296 * 2);
  unsigned short* w3h = (unsigned short*)take(221184 * 2);
  unsigned short* w3l = (unsigned short*)take(221184 * 2);
  unsigned short* w4h = (unsigned short*)take(884736 * 2);
  unsigned short* w4l = (unsigned short*)take(884736 * 2);
  unsigned short* w5h = (unsigned short*)take(3538944 * 2);
  unsigned short* w5l = (unsigned short*)take(3538944 * 2);
  float* woutT = (float*)take(131072 * 4);
  float* bs1 = (float*)take(32 * 4);
  float* bs2 = (float*)take(64 * 4);
  float* bs3 = (float*)take(128 * 4);
  float* bs4 = (float*)take(256 * 4);
  float* bs5 = (float*)take(512 * 4);
  unsigned short* h1h = (unsigned short*)take((size_t)16777216 * 2);
  unsigned short* h1l = (unsigned short*)take((size_t)16777216 * 2);
  unsigned short* h2h = (unsigned short*)take((size_t)4194304 * 2);
  unsigned short* h2l = (unsigned short*)take((size_t)4194304 * 2);

  char* AR = (char*)h1h;  // h1 dead after stage 2
  float* p3 = (float*)AR;                        // 3*8192*128*4  = 12.58 MB
  float* p4 = (float*)AR;                        // 9*1024*256*4  =  9.44 MB
  float* p5 = (float*)AR;                        // 27*128*512*4  =  7.08 MB
  char* AR2 = AR + ((size_t)16 << 20);
  unsigned short* h3h = (unsigned short*)AR2;
  unsigned short* h3l = (unsigned short*)(AR2 + 2097152);
  unsigned short* h4h = (unsigned short*)(AR2 + 2 * 2097152);
  unsigned short* h4l = (unsigned short*)(AR2 + 2 * 2097152 + 524288);

  // --- all weight repacks, one launch ---
  repack_all<<<18886, 256, 0, stream>>>(
      w1, g1, bb1, m1, v1, w2, g2, bb2, m2, v2, w3, g3, bb3, m3, v3,
      w4, g4, bb4, m4, v4, w5, g5, bb5, m5, v5, w_out,
      wt1, w2h, w2l, w3h, w3l, w4h, w4l, w5h, w5l, woutT,
      bs1, bs2, bs3, bs4, bs5);

  // --- stage 1: pk_fma direct, [2,4,128^3] -> parity-split [2][8][32^3][32] ---
  conv1_direct<<<2048, 256, 0, stream>>>(x, wt1, bs1, h1h, h1l);

  // --- stage 2: MFMA M=65536 N=64, MREP=2, SK=1 fused ---
  conv_mfma<32, 64, 32, 1, 2><<<dim3(512, 1, 1), 256, 0, stream>>>(
      h1h, h1l, w2h, w2l, bs2, h2h, h2l, nullptr);

  // --- stage 3: MFMA M=8192 N=128, MREP=2, SK=3 ---
  conv_mfma<64, 128, 16, 3, 2><<<dim3(64, 2, 3), 256, 0, stream>>>(
      h2h, h2l, w3h, w3l, bs3, nullptr, nullptr, p3);
  reduce_split<128, 3, 8192, 16><<<4096, 256, 0, stream>>>(p3, bs3, h3h, h3l);

  // --- stage 4: MFMA M=1024 N=256, MREP=1, SK=9 ---
  conv_mfma<128, 256, 8, 9, 1><<<dim3(16, 4, 9), 256, 0, stream>>>(
      h3h, h3l, w4h, w4l, bs4, nullptr, nullptr, p4);
  reduce_split<256, 9, 1024, 8><<<1024, 256, 0, stream>>>(p4, bs4, h4h, h4l);

  // --- stage 5: MFMA M=128 N=512, MREP=1, SK=27 ---
  conv_mfma<256, 512, 4, 27, 1><<<dim3(2, 8, 27), 256, 0, stream>>>(
      h4h, h4l, w5h, w5l, bs5, nullptr, nullptr, p5);

  // --- fused stage-5 reduce + 1x1x1 conv ---
  final_fused<<<128, 256, 0, stream>>>(p5, bs5, woutT, (float*)d_out);
}

// Round 7
// 379.705 us; speedup vs baseline: 1.2299x; 1.2299x over previous
//
#include <hip/hip_runtime.h>

static constexpr float kEps = 1e-5f;

using bf16x8 = __attribute__((ext_vector_type(8))) short;
using f32x4 = __attribute__((ext_vector_type(4))) float;
using f32x2 = __attribute__((ext_vector_type(2))) float;

constexpr int ilog2(int n) { return n <= 1 ? 0 : 1 + ilog2(n / 2); }

// round-to-nearest-even f32 -> bf16 bits
__device__ inline unsigned bf_rne(float v) {
  unsigned u = __float_as_uint(v);
  return (u + 0x7FFFu + ((u >> 16) & 1u)) >> 16;
}
// split f32 into bf16 hi + bf16 lo (v ~= hi + lo)
__device__ inline void split_bf(float v, unsigned short& h, unsigned short& l) {
  unsigned hb = bf_rne(v);
  h = (unsigned short)hb;
  float hf = __uint_as_float(hb << 16);
  l = (unsigned short)bf_rne(v - hf);
}

// ---------------------------------------------------------------------------
// Repack bodies (device functions, fused into one kernel)
// ---------------------------------------------------------------------------
__device__ inline void repack_s1_body(int idx, const float* __restrict__ w,
                                      const float* __restrict__ g,
                                      const float* __restrict__ b,
                                      const float* __restrict__ m,
                                      const float* __restrict__ v,
                                      float* __restrict__ wT,
                                      float* __restrict__ bias) {
  constexpr int CIN = 4, COUT = 32, total = COUT * CIN * 27;
  if (idx < COUT) {
    float inv = g[idx] * rsqrtf(v[idx] + kEps);
    bias[idx] = b[idx] - m[idx] * inv;
  }
  if (idx < total) {
    int cout = idx % COUT;
    int ck = idx / COUT;
    int cin = ck / 27;
    int k = ck % 27;
    float inv = g[cout] * rsqrtf(v[cout] + kEps);
    wT[idx] = w[(cout * CIN + cin) * 27 + k] * inv;
  }
}

template <int CIN, int COUT>
__device__ inline void repack_bf_body(int idx, const float* __restrict__ w,
                                      const float* __restrict__ g,
                                      const float* __restrict__ b,
                                      const float* __restrict__ m,
                                      const float* __restrict__ v,
                                      unsigned short* __restrict__ wh,
                                      unsigned short* __restrict__ wl,
                                      float* __restrict__ bias) {
  constexpr int total = 27 * COUT * CIN;
  constexpr int LC = ilog2(CIN), LO = ilog2(COUT);
  if (idx < COUT) {
    float inv = g[idx] * rsqrtf(v[idx] + kEps);
    bias[idx] = b[idx] - m[idx] * inv;
  }
  if (idx < total) {
    int ci = idx & (CIN - 1);
    int t = idx >> LC;
    int co = t & (COUT - 1);
    int tap = t >> LO;
    float inv = g[co] * rsqrtf(v[co] + kEps);
    float val = w[((size_t)co * CIN + ci) * 27 + tap] * inv;
    unsigned short h, l;
    split_bf(val, h, l);
    wh[idx] = h;
    wl[idx] = l;
  }
}

// All weight repacks in ONE launch. Block ranges:
// [0,14) s1 | [14,230) s2 | [230,1094) s3 | [1094,4550) s4 |
// [4550,18374) s5 | [18374,18886) wout
__global__ __launch_bounds__(256) void repack_all(
    const float* w1, const float* g1, const float* b1, const float* m1, const float* v1,
    const float* w2, const float* g2, const float* b2, const float* m2, const float* v2,
    const float* w3, const float* g3, const float* b3, const float* m3, const float* v3,
    const float* w4, const float* g4, const float* b4, const float* m4, const float* v4,
    const float* w5, const float* g5, const float* b5, const float* m5, const float* v5,
    const float* w_out, float* wt1, unsigned short* w2h, unsigned short* w2l,
    unsigned short* w3h, unsigned short* w3l, unsigned short* w4h, unsigned short* w4l,
    unsigned short* w5h, unsigned short* w5l, float* woutT, float* bs1, float* bs2,
    float* bs3, float* bs4, float* bs5) {
  int blk = blockIdx.x;
  int tid = threadIdx.x;
  if (blk < 14) {
    repack_s1_body(blk * 256 + tid, w1, g1, b1, m1, v1, wt1, bs1);
  } else if (blk < 230) {
    repack_bf_body<32, 64>((blk - 14) * 256 + tid, w2, g2, b2, m2, v2, w2h, w2l, bs2);
  } else if (blk < 1094) {
    repack_bf_body<64, 128>((blk - 230) * 256 + tid, w3, g3, b3, m3, v3, w3h, w3l, bs3);
  } else if (blk < 4550) {
    repack_bf_body<128, 256>((blk - 1094) * 256 + tid, w4, g4, b4, m4, v4, w4h, w4l, bs4);
  } else if (blk < 18374) {
    repack_bf_body<256, 512>((blk - 4550) * 256 + tid, w5, g5, b5, m5, v5, w5h, w5l, bs5);
  } else {
    int idx = (blk - 18374) * 256 + tid;  // = c*256 + co
    int co = idx & 255;
    int c = idx >> 8;
    woutT[idx] = w_out[(size_t)co * 512 + c];
  }
}

// ---------------------------------------------------------------------------
// Stage 1: fp32 direct conv (cin=4), scalar fmaf (round-4 known-good body)
// -> parity-split channels-last bf16 hi/lo [b][pz][py][px][32^3][32]
// ---------------------------------------------------------------------------
__global__ __launch_bounds__(256) void conv1_direct(
    const float* __restrict__ in, const float* __restrict__ wT,
    const float* __restrict__ bias, unsigned short* __restrict__ outh,
    unsigned short* __restrict__ outl) {
  constexpr int DI = 128, CIN = 4, COUT = 32;
  int tid = blockIdx.x * 256 + threadIdx.x;
  int x = tid & 63;
  int t = tid >> 6;
  int y = t & 63;
  t >>= 6;
  int z = t & 63;
  int bb = t >> 6;

  float acc[COUT];
#pragma unroll
  for (int i = 0; i < COUT; ++i) acc[i] = 0.f;

  const float* inb = in + (size_t)bb * CIN * DI * DI * DI;
  for (int cin = 0; cin < CIN; ++cin) {
    const float* inc = inb + (size_t)cin * DI * DI * DI;
#pragma unroll
    for (int kz = 0; kz < 3; ++kz) {
      int iz = 2 * z + kz - 1;
      if (iz < 0) continue;
#pragma unroll
      for (int ky = 0; ky < 3; ++ky) {
        int iy = 2 * y + ky - 1;
        if (iy < 0) continue;
        const float* row = inc + ((size_t)iz * DI + iy) * DI;
#pragma unroll
        for (int kx = 0; kx < 3; ++kx) {
          int ix = 2 * x + kx - 1;
          float xv = (ix >= 0) ? row[ix] : 0.f;
          const float* wp = wT + ((size_t)cin * 27 + (kz * 3 + ky) * 3 + kx) * COUT;
#pragma unroll
          for (int i = 0; i < COUT; ++i) acc[i] = fmaf(xv, wp[i], acc[i]);
        }
      }
    }
  }
  int pidx = (z & 1) * 4 + (y & 1) * 2 + (x & 1);
  size_t sub = (((size_t)(z >> 1) * 32) + (y >> 1)) * 32 + (x >> 1);
  size_t op = (((size_t)bb * 8 + pidx) * 32768 + sub) * COUT;
#pragma unroll
  for (int i = 0; i < COUT; ++i) {
    float r = fmaxf(acc[i] + bias[i], 0.f);
    unsigned short h, l;
    split_bf(r, h, l);
    outh[op + i] = h;
    outl[op + i] = l;
  }
}

// ---------------------------------------------------------------------------
// MFMA implicit-GEMM conv (3x3x3 stride-2 pad-1) on parity-split input.
// Input: [b][pz][py][px][DO^3][CIN]. Tap (kz,ky,kx): p=(k!=1), d=(k==0).
// 3-product split: acc += Ah*Bh + Ah*Bl + Al*Bh (fp32 accumulate).
// Block = 4 waves; wave tile = (MREP*16) M x 64 N.
// ---------------------------------------------------------------------------
template <int CIN, int COUT, int DO, int SK, int MREP>
__global__ __launch_bounds__(256) void conv_mfma(
    const unsigned short* __restrict__ inh, const unsigned short* __restrict__ inl,
    const unsigned short* __restrict__ wh, const unsigned short* __restrict__ wl,
    const float* __restrict__ bias, unsigned short* __restrict__ outh,
    unsigned short* __restrict__ outl, float* __restrict__ partial) {
  constexpr int M = 2 * DO * DO * DO;
  constexpr int TAPS = 27 / SK;
  constexpr int KCPT = CIN / 32;
  constexpr int LD = ilog2(DO);
  constexpr int SUB = DO * DO * DO;

  const int lane = threadIdx.x & 63;
  const int wv = threadIdx.x >> 6;
  const int mWave = (blockIdx.x * 4 + wv) * (MREP * 16);
  const int nBase = blockIdx.y * 64;
  const int skid = blockIdx.z;
  const int mlane = lane & 15;
  const int kgrp = lane >> 4;

  int xf[MREP], yf[MREP], zf[MREP], bf_[MREP];
#pragma unroll
  for (int f = 0; f < MREP; ++f) {
    int m = mWave + f * 16 + mlane;
    xf[f] = m & (DO - 1);
    yf[f] = (m >> LD) & (DO - 1);
    zf[f] = (m >> (2 * LD)) & (DO - 1);
    bf_[f] = m >> (3 * LD);
  }

  f32x4 acc[MREP][4];
#pragma unroll
  for (int f = 0; f < MREP; ++f)
#pragma unroll
    for (int q = 0; q < 4; ++q) acc[f][q] = (f32x4){0.f, 0.f, 0.f, 0.f};

  for (int tp = 0; tp < TAPS; ++tp) {
    const int tap = skid * TAPS + tp;
    const int kz = tap / 9;
    const int kr = tap - kz * 9;
    const int ky = kr / 3;
    const int kx = kr - ky * 3;
    const int pidx = (kz != 1) * 4 + (ky != 1) * 2 + (kx != 1);
    const int dz = (kz == 0), dy = (ky == 0), dx = (kx == 0);

    const size_t woff = (size_t)tap * COUT * CIN + (size_t)(nBase + mlane) * CIN + kgrp * 8;
    const unsigned short* wbh = wh + woff;
    const unsigned short* wbl = wl + woff;

    long long aoff[MREP];
    bool valid[MREP];
#pragma unroll
    for (int f = 0; f < MREP; ++f) {
      int sx = xf[f] - dx, sy = yf[f] - dy, sz = zf[f] - dz;
      valid[f] = ((sx | sy | sz) >= 0);
      aoff[f] = ((long long)(bf_[f] * 8 + pidx) * SUB + (sz * DO + sy) * DO + sx) * CIN +
                kgrp * 8;
    }

#pragma unroll
    for (int kc = 0; kc < KCPT; ++kc) {
      bf16x8 Ah[MREP], Al[MREP];
#pragma unroll
      for (int f = 0; f < MREP; ++f) {
        Ah[f] = (bf16x8){0, 0, 0, 0, 0, 0, 0, 0};
        Al[f] = (bf16x8){0, 0, 0, 0, 0, 0, 0, 0};
        if (valid[f]) {
          Ah[f] = *reinterpret_cast<const bf16x8*>(inh + aoff[f] + kc * 32);
          Al[f] = *reinterpret_cast<const bf16x8*>(inl + aoff[f] + kc * 32);
        }
      }
#pragma unroll
      for (int nq = 0; nq < 4; ++nq) {
        bf16x8 Bh = *reinterpret_cast<const bf16x8*>(wbh + (size_t)nq * 16 * CIN + kc * 32);
        bf16x8 Bl = *reinterpret_cast<const bf16x8*>(wbl + (size_t)nq * 16 * CIN + kc * 32);
#pragma unroll
        for (int f = 0; f < MREP; ++f) {
          acc[f][nq] = __builtin_amdgcn_mfma_f32_16x16x32_bf16(Ah[f], Bh, acc[f][nq], 0, 0, 0);
          acc[f][nq] = __builtin_amdgcn_mfma_f32_16x16x32_bf16(Ah[f], Bl, acc[f][nq], 0, 0, 0);
          acc[f][nq] = __builtin_amdgcn_mfma_f32_16x16x32_bf16(Al[f], Bh, acc[f][nq], 0, 0, 0);
        }
      }
    }
  }

  if constexpr (SK == 1) {
    constexpr int HD = DO / 2;
#pragma unroll
    for (int f = 0; f < MREP; ++f) {
#pragma unroll
      for (int nq = 0; nq < 4; ++nq) {
        const int n = nBase + nq * 16 + mlane;
        const float bv = bias[n];
#pragma unroll
        for (int r = 0; r < 4; ++r) {
          const int mrow = mWave + f * 16 + kgrp * 4 + r;
          const int ox = mrow & (DO - 1);
          const int oy = (mrow >> LD) & (DO - 1);
          const int oz = (mrow >> (2 * LD)) & (DO - 1);
          const int ob = mrow >> (3 * LD);
          const int pp = (oz & 1) * 4 + (oy & 1) * 2 + (ox & 1);
          const size_t sub = (((size_t)(oz >> 1) * HD) + (oy >> 1)) * HD + (ox >> 1);
          const size_t addr = (((size_t)ob * 8 + pp) * (HD * HD * HD) + sub) * COUT + n;
          float vv = fmaxf(acc[f][nq][r] + bv, 0.f);
          unsigned short h, l;
          split_bf(vv, h, l);
          outh[addr] = h;
          outl[addr] = l;
        }
      }
    }
  } else {
#pragma unroll
    for (int f = 0; f < MREP; ++f) {
#pragma unroll
      for (int nq = 0; nq < 4; ++nq) {
        const int n = nBase + nq * 16 + mlane;
#pragma unroll
        for (int r = 0; r < 4; ++r) {
          const int mrow = mWave + f * 16 + kgrp * 4 + r;
          partial[((size_t)skid * M + mrow) * COUT + n] = acc[f][nq][r];
        }
      }
    }
  }
}

// ---------------------------------------------------------------------------
// Reduce split-K fp32 partials + bias + ReLU -> parity-split bf16 hi/lo
// ---------------------------------------------------------------------------
template <int COUT, int SK, int M, int DOP>
__global__ __launch_bounds__(256) void reduce_split(
    const float* __restrict__ partial, const float* __restrict__ bias,
    unsigned short* __restrict__ oh, unsigned short* __restrict__ ol) {
  constexpr int LD = ilog2(DOP);
  constexpr int HD = DOP / 2;
  int idx = blockIdx.x * 256 + threadIdx.x;  // mrow*COUT + n
  int n = idx & (COUT - 1);
  int mrow = idx / COUT;
  float s = 0.f;
#pragma unroll
  for (int k = 0; k < SK; ++k) s += partial[(size_t)k * M * COUT + idx];
  float v = fmaxf(s + bias[n], 0.f);
  const int ox = mrow & (DOP - 1);
  const int oy = (mrow >> LD) & (DOP - 1);
  const int oz = (mrow >> (2 * LD)) & (DOP - 1);
  const int ob = mrow >> (3 * LD);
  const int pp = (oz & 1) * 4 + (oy & 1) * 2 + (ox & 1);
  const size_t sub = (((size_t)(oz >> 1) * HD) + (oy >> 1)) * HD + (ox >> 1);
  const size_t addr = (((size_t)ob * 8 + pp) * (HD * HD * HD) + sub) * COUT + n;
  unsigned short h, l;
  split_bf(v, h, l);
  oh[addr] = h;
  ol[addr] = l;
}

// ---------------------------------------------------------------------------
// Fused: stage-5 split-K reduce (27 partials) + bias + ReLU + 1x1x1 conv.
// p5 layout [k][128][512]; wt [512][256]; out NCDHW [2][256][64]
// ---------------------------------------------------------------------------
__global__ __launch_bounds__(256) void final_fused(
    const float* __restrict__ p5, const float* __restrict__ bias,
    const float* __restrict__ wt, float* __restrict__ out) {
  __shared__ float h[512];
  int p = blockIdx.x;  // 0..127 = b*64 + s
  int t = threadIdx.x;
#pragma unroll
  for (int cc = 0; cc < 2; ++cc) {
    int c = t + cc * 256;
    float s = 0.f;
#pragma unroll
    for (int k = 0; k < 27; ++k) s += p5[((size_t)k * 128 + p) * 512 + c];
    h[c] = fmaxf(s + bias[c], 0.f);
  }
  __syncthreads();
  int b = p >> 6, sp = p & 63;
  float acc = 0.f;
#pragma unroll 8
  for (int c = 0; c < 512; ++c) acc = fmaf(h[c], wt[(size_t)c * 256 + t], acc);
  out[((size_t)b * 256 + t) * 64 + sp] = acc;
}

// ---------------------------------------------------------------------------
extern "C" void kernel_launch(void* const* d_in, const int* in_sizes, int n_in,
                              void* d_out, int out_size, void* d_ws,
                              size_t ws_size, hipStream_t stream) {
  const float* x = (const float*)d_in[0];
  const float* w1 = (const float*)d_in[1];
  const float* g1 = (const float*)d_in[2];
  const float* bb1 = (const float*)d_in[3];
  const float* m1 = (const float*)d_in[4];
  const float* v1 = (const float*)d_in[5];
  const float* w2 = (const float*)d_in[6];
  const float* g2 = (const float*)d_in[7];
  const float* bb2 = (const float*)d_in[8];
  const float* m2 = (const float*)d_in[9];
  const float* v2 = (const float*)d_in[10];
  const float* w3 = (const float*)d_in[11];
  const float* g3 = (const float*)d_in[12];
  const float* bb3 = (const float*)d_in[13];
  const float* m3 = (const float*)d_in[14];
  const float* v3 = (const float*)d_in[15];
  const float* w4 = (const float*)d_in[16];
  const float* g4 = (const float*)d_in[17];
  const float* bb4 = (const float*)d_in[18];
  const float* m4 = (const float*)d_in[19];
  const float* v4 = (const float*)d_in[20];
  const float* w5 = (const float*)d_in[21];
  const float* g5 = (const float*)d_in[22];
  const float* bb5 = (const float*)d_in[23];
  const float* m5 = (const float*)d_in[24];
  const float* v5 = (const float*)d_in[25];
  const float* w_out = (const float*)d_in[26];
  (void)in_sizes; (void)n_in; (void)out_size; (void)ws_size;

  char* base = (char*)d_ws;
  size_t off = 0;
  auto take = [&](size_t bytes) {
    char* p = base + off;
    off = (off + bytes + 255) & ~(size_t)255;
    return p;
  };
  float* wt1 = (float*)take(3456 * 4);
  unsigned short* w2h = (unsigned short*)take(55296 * 2);
  unsigned short* w2l = (unsigned short*)take(55296 * 2);
  unsigned short* w3h = (unsigned short*)take(221184 * 2);
  unsigned short* w3l = (unsigned short*)take(221184 * 2);
  unsigned short* w4h = (unsigned short*)take(884736 * 2);
  unsigned short* w4l = (unsigned short*)take(884736 * 2);
  unsigned short* w5h = (unsigned short*)take(3538944 * 2);
  unsigned short* w5l = (unsigned short*)take(3538944 * 2);
  float* woutT = (float*)take(131072 * 4);
  float* bs1 = (float*)take(32 * 4);
  float* bs2 = (float*)take(64 * 4);
  float* bs3 = (float*)take(128 * 4);
  float* bs4 = (float*)take(256 * 4);
  float* bs5 = (float*)take(512 * 4);
  unsigned short* h1h = (unsigned short*)take((size_t)16777216 * 2);
  unsigned short* h1l = (unsigned short*)take((size_t)16777216 * 2);
  unsigned short* h2h = (unsigned short*)take((size_t)4194304 * 2);
  unsigned short* h2l = (unsigned short*)take((size_t)4194304 * 2);

  char* AR = (char*)h1h;  // h1 (67 MB) dead after stage 2; reuse for partials
  float* p3 = (float*)AR;                        // 9*8192*128*4  = 37.75 MB
  float* p4 = (float*)AR;                        // 9*1024*256*4  =  9.44 MB
  float* p5 = (float*)AR;                        // 27*128*512*4  =  7.08 MB
  char* AR2 = AR + ((size_t)40 << 20);           // past p3
  unsigned short* h3h = (unsigned short*)AR2;
  unsigned short* h3l = (unsigned short*)(AR2 + 2097152);
  unsigned short* h4h = (unsigned short*)(AR2 + 2 * 2097152);
  unsigned short* h4l = (unsigned short*)(AR2 + 2 * 2097152 + 524288);

  // --- all weight repacks, one launch ---
  repack_all<<<18886, 256, 0, stream>>>(
      w1, g1, bb1, m1, v1, w2, g2, bb2, m2, v2, w3, g3, bb3, m3, v3,
      w4, g4, bb4, m4, v4, w5, g5, bb5, m5, v5, w_out,
      wt1, w2h, w2l, w3h, w3l, w4h, w4l, w5h, w5l, woutT,
      bs1, bs2, bs3, bs4, bs5);

  // --- stage 1: fp32 direct, [2,4,128^3] -> parity-split [2][8][32^3][32] ---
  conv1_direct<<<2048, 256, 0, stream>>>(x, wt1, bs1, h1h, h1l);

  // --- stage 2: MFMA M=65536 N=64, MREP=4, SK=1 fused ---
  conv_mfma<32, 64, 32, 1, 4><<<dim3(256, 1, 1), 256, 0, stream>>>(
      h1h, h1l, w2h, w2l, bs2, h2h, h2l, nullptr);

  // --- stage 3: MFMA M=8192 N=128, MREP=4, SK=9 (576 blocks) ---
  conv_mfma<64, 128, 16, 9, 4><<<dim3(32, 2, 9), 256, 0, stream>>>(
      h2h, h2l, w3h, w3l, bs3, nullptr, nullptr, p3);
  reduce_split<128, 9, 8192, 16><<<4096, 256, 0, stream>>>(p3, bs3, h3h, h3l);

  // --- stage 4: MFMA M=1024 N=256, MREP=2, SK=9 (288 blocks) ---
  conv_mfma<128, 256, 8, 9, 2><<<dim3(8, 4, 9), 256, 0, stream>>>(
      h3h, h3l, w4h, w4l, bs4, nullptr, nullptr, p4);
  reduce_split<256, 9, 1024, 8><<<1024, 256, 0, stream>>>(p4, bs4, h4h, h4l);

  // --- stage 5: MFMA M=128 N=512, MREP=1, SK=27 (432 blocks) ---
  conv_mfma<256, 512, 4, 27, 1><<<dim3(2, 8, 27), 256, 0, stream>>>(
      h4h, h4l, w5h, w5l, bs5, nullptr, nullptr, p5);

  // --- fused stage-5 reduce + 1x1x1 conv ---
  final_fused<<<128, 256, 0, stream>>>(p5, bs5, woutT, (float*)d_out);
}